// Round 2
// 344.898 us; speedup vs baseline: 1.0440x; 1.0440x over previous
//
#include <hip/hip_runtime.h>
#include <hip/hip_bf16.h>

#define N_NODES 100000
#define N_EDGES 3200000
#define IN_CH   128
#define HID     32
#define NB      512              // dst buckets for CSR build
#define NPB     196              // nodes per bucket (512*196 >= 100000)
#define CAP     8192             // fixed per-bucket region capacity (mean 6250, 24 sigma)
#define CHUNK   8192             // edges per block in bucket_scatter2

// --- bf16x2 pack/unpack (round-to-nearest-even) ----------------------------
__device__ __forceinline__ unsigned int pack_bf16x2(float a, float b) {
    unsigned int ua = __float_as_uint(a);
    unsigned int ub = __float_as_uint(b);
    ua = (ua + 0x7FFFu + ((ua >> 16) & 1u)) >> 16;
    ub = (ub + 0x7FFFu + ((ub >> 16) & 1u)) >> 16;
    return (ua & 0xFFFFu) | (ub << 16);
}
__device__ __forceinline__ float bf_lo(unsigned int v) { return __uint_as_float(v << 16); }
__device__ __forceinline__ float bf_hi(unsigned int v) { return __uint_as_float(v & 0xFFFF0000u); }

// ---------------------------------------------------------------------------
// Detect whether edge_index is int64 (odd 32-bit words all zero) or int32.
// ---------------------------------------------------------------------------
__global__ __launch_bounds__(256) void detect_idx(const int* __restrict__ ei,
                                                  int* __restrict__ flag) {
    __shared__ int nz;
    if (threadIdx.x == 0) nz = 0;
    __syncthreads();
    if (ei[2 * threadIdx.x + 1] != 0) atomicAdd(&nz, 1);
    __syncthreads();
    if (threadIdx.x == 0) flag[0] = (nz == 0) ? 1 : 0;
}

__device__ __forceinline__ int edge_at(const int* __restrict__ ei, int idx64,
                                       size_t pos) {
    if (idx64) return (int)((const long long*)ei)[pos];
    return ei[pos];
}

__global__ __launch_bounds__(256) void bcur_init(int* __restrict__ bcur) {
    int b = blockIdx.x * 256 + threadIdx.x;
    if (b < NB) bcur[b] = b * CAP;
}

// ---------------------------------------------------------------------------
// Scatter edges into fixed-capacity dst-bucket regions of ebuf, 4 B packed
// (s<<8)|dloc. Block-level pre-aggregation keeps global atomics to one per
// (block, nonzero-bucket).
// ---------------------------------------------------------------------------
__global__ __launch_bounds__(256) void bucket_scatter2(
    const int* __restrict__ ei,
    const int* __restrict__ flag,
    int* __restrict__ bcur,
    unsigned int* __restrict__ ebuf) {
    __shared__ unsigned int   pk[CHUNK];     // 32 KB  packed (s<<8)|dloc
    __shared__ unsigned short bb[CHUNK];     // 16 KB  bucket id per edge
    __shared__ int cnt[NB];                  // 2 KB   block histogram
    __shared__ int cnt2[NB];                 // 2 KB   scatter cursor
    __shared__ int base_l[NB];               // 2 KB   reserved global base

    int t = threadIdx.x;
    for (int j = t; j < NB; j += 256) { cnt[j] = 0; cnt2[j] = 0; }
    __syncthreads();

    int e0 = blockIdx.x * CHUNK;
    int nE = N_EDGES - e0; if (nE > CHUNK) nE = CHUNK;
    int idx64 = flag[0];

    for (int i = t; i < nE; i += 256) {
        unsigned int s = (unsigned int)edge_at(ei, idx64, (size_t)(e0 + i));
        unsigned int d = (unsigned int)edge_at(ei, idx64, (size_t)N_EDGES + e0 + i);
        unsigned int b = d / NPB;            // compile-time const -> magic mul
        pk[i] = (s << 8) | (d - b * NPB);
        bb[i] = (unsigned short)b;
        atomicAdd(&cnt[b], 1);               // LDS atomic
    }
    __syncthreads();

    for (int j = t; j < NB; j += 256) {
        int c = cnt[j];
        if (c > 0) base_l[j] = atomicAdd(&bcur[j], c);   // one per bucket
    }
    __syncthreads();

    for (int i = t; i < nE; i += 256) {
        int b = bb[i];
        int p = atomicAdd(&cnt2[b], 1);      // LDS atomic
        ebuf[base_l[b] + p] = pk[i];
    }
}

// ---------------------------------------------------------------------------
// Exclusive scan of the 512 final bucket counts -> gbase (single block).
// ---------------------------------------------------------------------------
__global__ __launch_bounds__(512) void scan_buckets(const int* __restrict__ bcur,
                                                    int* __restrict__ gbase,
                                                    int* __restrict__ rowptr) {
    __shared__ int tmp[512];
    int t = threadIdx.x;
    int c = bcur[t] - t * CAP;               // this bucket's edge count
    tmp[t] = c;
    __syncthreads();
    for (int off = 1; off < 512; off <<= 1) {
        int x = 0;
        if (t >= off) x = tmp[t - off];
        __syncthreads();
        if (t >= off) tmp[t] += x;
        __syncthreads();
    }
    gbase[t] = tmp[t] - c;                   // exclusive
    if (t == 511) rowptr[N_NODES] = N_EDGES;
}

// ---------------------------------------------------------------------------
// Per-bucket finalize: local dst histogram -> dinv, local scan -> rowptr,
// LDS scatter -> coalesced col.
// ---------------------------------------------------------------------------
__global__ __launch_bounds__(256) void fill_csr3(
    const int* __restrict__ bcur,
    const int* __restrict__ gbase,
    const unsigned int* __restrict__ ebuf,
    int* __restrict__ rowptr,
    float* __restrict__ dinv,
    int* __restrict__ col) {
    __shared__ int lhist[NPB];
    __shared__ int lrow[NPB];      // exclusive offsets, then scatter cursors
    __shared__ int tmp[256];
    __shared__ int lbuf[CAP];      // 32 KB
    int b = blockIdx.x;
    int t = threadIdx.x;
    int n0 = b * NPB;  if (n0 > N_NODES) n0 = N_NODES;
    int n1 = n0 + NPB; if (n1 > N_NODES) n1 = N_NODES;
    int nn  = n1 - n0;
    int cnt = bcur[b] - b * CAP;
    int E0  = gbase[b];
    const unsigned int* reg = ebuf + (size_t)b * CAP;

    for (int j = t; j < NPB; j += 256) lhist[j] = 0;
    __syncthreads();
    for (int i = t; i < cnt; i += 256)
        atomicAdd(&lhist[reg[i] & 255u], 1);     // LDS histogram
    __syncthreads();

    // fused make_dinv (self-loop +1)
    for (int j = t; j < nn; j += 256)
        dinv[n0 + j] = rsqrtf((float)(lhist[j] + 1));

    // exclusive scan of lhist[0..nn) (NPB < 256: one Hillis-Steele pass)
    int v = (t < NPB) ? lhist[t] : 0;
    tmp[t] = v;
    __syncthreads();
    for (int off = 1; off < 256; off <<= 1) {
        int x = 0;
        if (t >= off) x = tmp[t - off];
        __syncthreads();
        if (t >= off) tmp[t] += x;
        __syncthreads();
    }
    if (t < NPB) lrow[t] = tmp[t] - v;
    __syncthreads();

    for (int j = t; j < nn; j += 256)
        rowptr[n0 + j] = E0 + lrow[j];
    __syncthreads();               // rowptr reads lrow before cursor mutation

    for (int i = t; i < cnt; i += 256) {
        unsigned int e = reg[i];
        int p = atomicAdd(&lrow[e & 255u], 1);
        lbuf[p] = (int)(e >> 8);
    }
    __syncthreads();
    for (int j = t; j < cnt; j += 256)
        col[E0 + j] = lbuf[j];
}

// ---------------------------------------------------------------------------
// GEMM1: h1b[n][c2] = pack_bf16( (x[n]·W1[:,2c2..2c2+1]) * dinv[n] )
// ---------------------------------------------------------------------------
__global__ __launch_bounds__(256) void gemm1_scale(
    const float* __restrict__ x,
    const float* __restrict__ W1,
    const float* __restrict__ dinv,
    unsigned int* __restrict__ h1b) {
    __shared__ float w[IN_CH * HID];   // 16 KB
    for (int i = threadIdx.x; i < IN_CH * HID; i += 256)
        w[i] = W1[i];
    __syncthreads();

    int node = blockIdx.x * 8 + (threadIdx.x >> 5);
    int c    = threadIdx.x & 31;
    if (node >= N_NODES) return;

    const float4* xr = reinterpret_cast<const float4*>(x + (size_t)node * IN_CH);
    float acc = 0.0f;
#pragma unroll
    for (int k4 = 0; k4 < IN_CH / 4; ++k4) {
        float4 v = xr[k4];
        acc += v.x * w[(k4 * 4 + 0) * HID + c]
             + v.y * w[(k4 * 4 + 1) * HID + c]
             + v.z * w[(k4 * 4 + 2) * HID + c]
             + v.w * w[(k4 * 4 + 3) * HID + c];
    }
    float val = acc * dinv[node];
    int c2 = c & 15;
    float lo = __shfl(val, 2 * c2, 32);
    float hi = __shfl(val, 2 * c2 + 1, 32);
    if (c < 16) h1b[(size_t)node * 16 + c2] = pack_bf16x2(lo, hi);
}

// ---------------------------------------------------------------------------
// Layer-1 aggregate, wave-per-node with uint4 gathers:
//   lane = 64 lanes/node; r = lane>>2 (edge slot 0..15), q = lane&3
//   (row quarter: channels 8q..8q+7). One col load instruction fetches 64
//   edge indices; one gather instruction fetches 16 rows (1 KB in flight).
//   Then shfl_xor reduce over r, relu, GEMM2 split across all 64 lanes.
// ---------------------------------------------------------------------------
__global__ __launch_bounds__(256) void aggregate1(
    const int* __restrict__ rowptr,
    const int* __restrict__ col,
    const unsigned int* __restrict__ h1b,
    const float* __restrict__ dinv,
    const float* __restrict__ b1,
    const float* __restrict__ W2,
    unsigned int* __restrict__ h3b) {
    __shared__ float w2s[HID * HID];   // 4 KB
    for (int i = threadIdx.x; i < HID * HID; i += 256)
        w2s[i] = W2[i];
    __syncthreads();

    int node = blockIdx.x * 4 + (threadIdx.x >> 6);
    if (node >= N_NODES) return;
    int lane = threadIdx.x & 63;
    int r = lane >> 2;                 // edge slot within a 64-edge chunk
    int q = lane & 3;                  // quarter of the 64-byte row

    int e0 = rowptr[node];
    int e1 = rowptr[node + 1];

    float acc[8];
#pragma unroll
    for (int i = 0; i < 8; ++i) acc[i] = 0.f;

    if (r == 0) {                      // self-loop, counted once
        uint4 sv = *reinterpret_cast<const uint4*>(h1b + (size_t)node * 16 + 4 * q);
        acc[0] += bf_lo(sv.x); acc[1] += bf_hi(sv.x);
        acc[2] += bf_lo(sv.y); acc[3] += bf_hi(sv.y);
        acc[4] += bf_lo(sv.z); acc[5] += bf_hi(sv.z);
        acc[6] += bf_lo(sv.w); acc[7] += bf_hi(sv.w);
    }

    for (int e = e0; e < e1; e += 64) {
        int n = e1 - e;                            // wave-uniform remaining
        int li = lane < n ? lane : 0;
        int cv = col[e + li];                      // 64 edge indices / instr
#pragma unroll
        for (int u = 0; u < 4; ++u) {
            if (u * 16 < n) {                      // wave-uniform slot skip
                int s = __shfl(cv, u * 16 + r, 64);
                if (u * 16 + r < n) {
                    uint4 v = *reinterpret_cast<const uint4*>(
                        h1b + (size_t)s * 16 + 4 * q);
                    acc[0] += bf_lo(v.x); acc[1] += bf_hi(v.x);
                    acc[2] += bf_lo(v.y); acc[3] += bf_hi(v.y);
                    acc[4] += bf_lo(v.z); acc[5] += bf_hi(v.z);
                    acc[6] += bf_lo(v.w); acc[7] += bf_hi(v.w);
                }
            }
        }
    }

    // reduce over the 16 edge slots (keep q partition)
#pragma unroll
    for (int off = 4; off < 64; off <<= 1) {
#pragma unroll
        for (int i = 0; i < 8; ++i) acc[i] += __shfl_xor(acc[i], off, 64);
    }

    float dn = dinv[node];
    float h2[8];
#pragma unroll
    for (int i = 0; i < 8; ++i) {
        float v = acc[i] * dn + b1[8 * q + i];
        h2[i] = v > 0.f ? v : 0.f;
    }

    // GEMM2 split: t = lane>>4 covers j = 8t..8t+7; reduce over t via xor.
    int t  = lane >> 4;
    int c2 = lane & 15;
    float a2e = 0.f, a2o = 0.f;
#pragma unroll
    for (int jj = 0; jj < 8; ++jj) {
        int j = 8 * t + jj;
        float hj = __shfl(h2[jj], t, 64);   // lane t holds channels 8t+jj
        a2e += hj * w2s[j * HID + 2 * c2];
        a2o += hj * w2s[j * HID + 2 * c2 + 1];
    }
    a2e += __shfl_xor(a2e, 16, 64); a2e += __shfl_xor(a2e, 32, 64);
    a2o += __shfl_xor(a2o, 16, 64); a2o += __shfl_xor(a2o, 32, 64);
    if (lane < 16)
        h3b[(size_t)node * 16 + c2] = pack_bf16x2(a2e * dn, a2o * dn);
}

// ---------------------------------------------------------------------------
// Layer-2 aggregate, same wave-per-node uint4-gather structure + epilogue2.
// ---------------------------------------------------------------------------
__global__ __launch_bounds__(256) void aggregate2(
    const int* __restrict__ rowptr,
    const int* __restrict__ col,
    const unsigned int* __restrict__ h3b,
    const float* __restrict__ dinv,
    const float* __restrict__ b2,
    float* __restrict__ out) {
    int node = blockIdx.x * 4 + (threadIdx.x >> 6);
    if (node >= N_NODES) return;
    int lane = threadIdx.x & 63;
    int r = lane >> 2;
    int q = lane & 3;

    int e0 = rowptr[node];
    int e1 = rowptr[node + 1];

    float acc[8];
#pragma unroll
    for (int i = 0; i < 8; ++i) acc[i] = 0.f;

    if (r == 0) {                      // self-loop
        uint4 sv = *reinterpret_cast<const uint4*>(h3b + (size_t)node * 16 + 4 * q);
        acc[0] += bf_lo(sv.x); acc[1] += bf_hi(sv.x);
        acc[2] += bf_lo(sv.y); acc[3] += bf_hi(sv.y);
        acc[4] += bf_lo(sv.z); acc[5] += bf_hi(sv.z);
        acc[6] += bf_lo(sv.w); acc[7] += bf_hi(sv.w);
    }

    for (int e = e0; e < e1; e += 64) {
        int n = e1 - e;
        int li = lane < n ? lane : 0;
        int cv = col[e + li];
#pragma unroll
        for (int u = 0; u < 4; ++u) {
            if (u * 16 < n) {
                int s = __shfl(cv, u * 16 + r, 64);
                if (u * 16 + r < n) {
                    uint4 v = *reinterpret_cast<const uint4*>(
                        h3b + (size_t)s * 16 + 4 * q);
                    acc[0] += bf_lo(v.x); acc[1] += bf_hi(v.x);
                    acc[2] += bf_lo(v.y); acc[3] += bf_hi(v.y);
                    acc[4] += bf_lo(v.z); acc[5] += bf_hi(v.z);
                    acc[6] += bf_lo(v.w); acc[7] += bf_hi(v.w);
                }
            }
        }
    }

#pragma unroll
    for (int off = 4; off < 64; off <<= 1) {
#pragma unroll
        for (int i = 0; i < 8; ++i) acc[i] += __shfl_xor(acc[i], off, 64);
    }

    float dn = dinv[node];
    float o0 = acc[0] * dn + b2[8 * q + 0];
    float o1 = acc[1] * dn + b2[8 * q + 1];
    float o2 = acc[2] * dn + b2[8 * q + 2];
    float o3 = acc[3] * dn + b2[8 * q + 3];
    float o4 = acc[4] * dn + b2[8 * q + 4];
    float o5 = acc[5] * dn + b2[8 * q + 5];
    float o6 = acc[6] * dn + b2[8 * q + 6];
    float o7 = acc[7] * dn + b2[8 * q + 7];

    float* op = out + (size_t)node * 32 + 8 * q;
    if (r == 0) {
        *reinterpret_cast<float4*>(op)     = make_float4(o0, o1, o2, o3);
    } else if (r == 1) {
        *reinterpret_cast<float4*>(op + 4) = make_float4(o4, o5, o6, o7);
    }
}

// ---------------------------------------------------------------------------
extern "C" void kernel_launch(void* const* d_in, const int* in_sizes, int n_in,
                              void* d_out, int out_size, void* d_ws, size_t ws_size,
                              hipStream_t stream) {
    const float* x  = (const float*)d_in[0];
    const int*   ei = (const int*)d_in[1];
    const float* W1 = (const float*)d_in[2];
    const float* b1 = (const float*)d_in[3];
    const float* W2 = (const float*)d_in[4];
    const float* b2 = (const float*)d_in[5];
    float* out = (float*)d_out;

    // workspace: flag[64] | bcur[512] | gbase[512] | rowptr[N+1] | col[E] |
    //            dinv[N] | region{ h1b (6.4MB) | h3b (6.4MB) } where ebuf
    //            (512*CAP u32 = 16 MiB) ALIASES the region (dead by gemm1).
    // Total ~31 MiB.
    int*          flag   = (int*)d_ws;
    int*          bcur   = flag + 64;
    int*          gbase  = bcur + NB;
    int*          rowptr = gbase + NB;
    int*          col    = rowptr + (N_NODES + 1);
    float*        dinv   = (float*)(col + N_EDGES);
    unsigned int* h1b    = (unsigned int*)(dinv + N_NODES);
    unsigned int* h3b    = h1b + (size_t)N_NODES * 16;
    unsigned int* ebuf   = h1b;                          // alias, dead by gemm1

    const int gemmBlocks  = (N_NODES + 7) / 8;               // 12500
    const int aggBlocks   = (N_NODES + 3) / 4;               // 25000 (4 nodes/block)
    const int chunkBlocks = (N_EDGES + CHUNK - 1) / CHUNK;   // 391

    detect_idx<<<1, 256, 0, stream>>>(ei, flag);

    // bucketed CSR build (single pass over edge_index)
    bcur_init<<<(NB + 255) / 256, 256, 0, stream>>>(bcur);
    bucket_scatter2<<<chunkBlocks, 256, 0, stream>>>(ei, flag, bcur, ebuf);
    scan_buckets<<<1, 512, 0, stream>>>(bcur, gbase, rowptr);
    fill_csr3<<<NB, 256, 0, stream>>>(bcur, gbase, ebuf, rowptr, dinv, col);

    // layer 1 (+ fused relu + gemm2)
    gemm1_scale<<<gemmBlocks, 256, 0, stream>>>(x, W1, dinv, h1b);
    aggregate1<<<aggBlocks, 256, 0, stream>>>(rowptr, col, h1b, dinv, b1, W2, h3b);

    // layer 2 (+ fused epilogue)
    aggregate2<<<aggBlocks, 256, 0, stream>>>(rowptr, col, h3b, dinv, b2, out);
}